// Round 5
// baseline (175.817 us; speedup 1.0000x reference)
//
#include <hip/hip_runtime.h>
#include <hip/hip_cooperative_groups.h>
#include <cstdint>

namespace cg = cooperative_groups;

// DifferentiableStarPlanner, MI355X — round 4 resubmit (R4 bench never acquired a GPU).
// R3 post-mortem: 12-dispatch chain = 159us, but desk model says ~45us of real
// work; residual is inter-dispatch overhead (serial dependency chain). Fuse all
// 8 KS-step chunks into ONE cooperative kernel (16 blocks, grid.sync at chunk
// boundaries). Costs persist in registers across all 64 steps. Cross-chunk halo
// exchange ping-pongs g<->wsg so one grid.sync per chunk is race-free:
// chunk k reads buf[k&1], writes buf[(k+1)&1]; k_init g_inits BOTH buffers;
// active tile set grows monotonically, so inactive tiles hold g_init in both.
// Geometry (TS=33, KS=8, W2=49, 2x4 strips) identical to the verified R3 kernel.

#define HH 1024
#define WW 1024
#define FINF 1.0e7f
#define FOB  1.0e4f
#define FEPS 1e-12f
#define BIGC 1.0e30f

#define MAXR 132              // max region edge on tiled path (need 2*64+1=129)
#define TS   33               // owned tile edge (4x4 tiles cover MAXR)
#define KS   8                // steps per chunk = halo width
#define NSUB 8                // KS*NSUB = 64 steps max on tiled path
#define W2   (TS + 2*KS)      // 49: working tile edge
#define LROWS 52
#define LSTR  60
#define SRB 2                 // strip rows/thread
#define SCB 4                 // strip cols/thread
#define NSR 25                // ceil(W2/SRB)
#define NSC 13                // ceil(W2/SCB)
#define BD  384               // block threads (>= NSR*NSC=325)
#define NBLK 16

// -------- per-cell, per-direction path costs (exact port of calculateLocalPathCosts)
__device__ __forceinline__ void cost8(const float* __restrict__ ob,
                                      const float* __restrict__ yco,
                                      const float* __restrict__ xco,
                                      int gi, int gj, float c[8])
{
  const int jm = gj > 0      ? gj - 1 : 0;
  const int jp = gj < WW - 1 ? gj + 1 : WW - 1;
  const int im = gi > 0      ? gi - 1 : 0;
  const int ip = gi < HH - 1 ? gi + 1 : HH - 1;
  const float xc = xco[gi * WW + gj];
  const float yc = yco[gi * WW + gj];
  const float dl = xc - xco[gi * WW + jm]; const float l = dl * dl;
  const float dr = xc - xco[gi * WW + jp]; const float r = dr * dr;
  const float du = yc - yco[im * WW + gj]; const float u = du * du;
  const float dd = yc - yco[ip * WW + gj]; const float d = dd * dd;
  const float oc  = ob[gi * WW + gj];
  const float oNW = ob[im * WW + jm], oN = ob[im * WW + gj], oNE = ob[im * WW + jp];
  const float oE  = ob[gi * WW + jp];
  const float oSW = ob[ip * WW + jm], oS = ob[ip * WW + gj], oSE = ob[ip * WW + jp];
  // dir order: 0 NW(-1,-1) 1 W(0,-1) 2 SW(1,-1) 3 N(-1,0) 4 S(1,0) 5 NE(-1,1) 6 E(0,1) 7 SE(1,1)
  c[0] = sqrtf(l + u + FEPS) + FOB * fmaxf(oNW, oc);
  c[1] = sqrtf(l + FEPS)     + FOB * fmaxf(oN , oc);  // reference quirk: W move uses N obstacle
  c[2] = sqrtf(l + d + FEPS) + FOB * fmaxf(oSW, oc);
  c[3] = sqrtf(u + FEPS)     + FOB * fmaxf(oN , oc);
  c[4] = sqrtf(d + FEPS)     + FOB * fmaxf(oS , oc);
  c[5] = sqrtf(r + u + FEPS) + FOB * fmaxf(oNE, oc);
  c[6] = sqrtf(r + FEPS)     + FOB * fmaxf(oE , oc);
  c[7] = sqrtf(r + d + FEPS) + FOB * fmaxf(oSE, oc);
}

__device__ __forceinline__ bool region_of(const unsigned* __restrict__ bb, int ns,
                                          int& i0, int& i1, int& j0, int& j1,
                                          int& ri0, int& ri1, int& rj0, int& rj1,
                                          int& RH, int& RW)
{
  if (bb[0] > (unsigned)(HH - 1)) return false;
  i0 = (int)bb[0]; i1 = 4096 - (int)bb[1];
  j0 = (int)bb[2]; j1 = 4096 - (int)bb[3];
  ri0 = i0 - ns; if (ri0 < 0) ri0 = 0;
  ri1 = i1 + ns; if (ri1 > HH - 1) ri1 = HH - 1;
  rj0 = j0 - ns; if (rj0 < 0) rj0 = 0;
  rj1 = j1 + ns; if (rj1 > WW - 1) rj1 = WW - 1;
  RH = ri1 - ri0 + 1; RW = rj1 - rj0 + 1;
  return true;
}

// -------- K0: bbox init (ws re-poisoned every call)
__global__ void k_bbinit(unsigned int* bb)
{
  if (threadIdx.x < 4) bb[threadIdx.x] = 0xFFFFFFFFu;
}

// -------- K1: g_init into BOTH ping-pong buffers + start bbox via atomicMin
__global__ void k_init(const float* __restrict__ start, float* __restrict__ g,
                       unsigned int* bb, float* __restrict__ wsg, int ws_ok)
{
  const int idx = blockIdx.x * blockDim.x + threadIdx.x;     // over H*W/4
  const float4 s = reinterpret_cast<const float4*>(start)[idx];
  float4 o;
  o.x = fminf(fmaxf(FINF * (1.0f - s.x), 0.0f), FINF);
  o.y = fminf(fmaxf(FINF * (1.0f - s.y), 0.0f), FINF);
  o.z = fminf(fmaxf(FINF * (1.0f - s.z), 0.0f), FINF);
  o.w = fminf(fmaxf(FINF * (1.0f - s.w), 0.0f), FINF);
  reinterpret_cast<float4*>(g)[idx] = o;
  if (ws_ok) reinterpret_cast<float4*>(wsg)[idx] = o;
  if (s.x > 0.0f || s.y > 0.0f || s.z > 0.0f || s.w > 0.0f) {
    const int base = idx * 4;
    const int r  = base >> 10;
    const int c0 = base & (WW - 1);
    atomicMin(bb + 0, (unsigned)r);
    atomicMin(bb + 1, (unsigned)(4096 - r));
    if (s.x > 0.0f) { atomicMin(bb + 2, (unsigned)(c0 + 0)); atomicMin(bb + 3, (unsigned)(4096 - (c0 + 0))); }
    if (s.y > 0.0f) { atomicMin(bb + 2, (unsigned)(c0 + 1)); atomicMin(bb + 3, (unsigned)(4096 - (c0 + 1))); }
    if (s.z > 0.0f) { atomicMin(bb + 2, (unsigned)(c0 + 2)); atomicMin(bb + 3, (unsigned)(4096 - (c0 + 2))); }
    if (s.w > 0.0f) { atomicMin(bb + 2, (unsigned)(c0 + 3)); atomicMin(bb + 3, (unsigned)(4096 - (c0 + 3))); }
  }
}

// -------- K2: single cooperative kernel — all NSUB chunks, grid.sync between
__global__ __launch_bounds__(BD, 1) void k_coop(
    const float* __restrict__ ob, const float* __restrict__ co,
    const unsigned* __restrict__ bb, float* __restrict__ g,
    const int* __restrict__ nsp, float* __restrict__ wsg, int ws_ok)
{
  cg::grid_group grid = cg::this_grid();
  __shared__ float L[2][LROWS * LSTR];
  const float* yco = co;
  const float* xco = co + HH * WW;
  const int tid = threadIdx.x;

  int ns = *nsp; if (ns < 0) ns = 0;
  int i0,i1,j0,j1, ri0,ri1,rj0,rj1, RH,RW;
  if (!region_of(bb, ns, i0,i1,j0,j1, ri0,ri1,rj0,rj1, RH,RW)) return;  // grid-uniform

  // ---- defensive fallback (never triggered by harness input): global Jacobi
  if (ns > KS * NSUB || RH > MAXR || RW > MAXR) {                        // grid-uniform
    if (!ws_ok) return;
    const int gt = blockIdx.x * BD + tid, nthr = NBLK * BD;
    for (int s = 0; s < ns; ++s) {
      const float* src = (s & 1) ? wsg : g;
      float*       dst = (s & 1) ? g : wsg;
      for (int k = gt; k < HH * WW; k += nthr) {
        const int gi = k >> 10, gj = k & (WW - 1);
        float c[8]; cost8(ob, yco, xco, gi, gj, c);
        const int im = gi > 0 ? gi - 1 : 0, ip = gi < HH - 1 ? gi + 1 : HH - 1;
        const int jm = gj > 0 ? gj - 1 : 0, jp = gj < WW - 1 ? gj + 1 : WW - 1;
        float m = src[k];
        m = fminf(m, src[im * WW + jm] + c[0]); m = fminf(m, src[gi * WW + jm] + c[1]);
        m = fminf(m, src[ip * WW + jm] + c[2]); m = fminf(m, src[im * WW + gj] + c[3]);
        m = fminf(m, src[ip * WW + gj] + c[4]); m = fminf(m, src[im * WW + jp] + c[5]);
        m = fminf(m, src[gi * WW + jp] + c[6]); m = fminf(m, src[ip * WW + jp] + c[7]);
        dst[k] = m;
      }
      grid.sync();
    }
    if (ns & 1) { for (int k = gt; k < HH * WW; k += nthr) g[k] = wsg[k]; }
    return;
  }

  // ---- tile geometry (4x4 tiles of TS over the region)
  const int by = blockIdx.x >> 2, bx = blockIdx.x & 3;
  const int tr0 = ri0 + by * TS, tc0 = rj0 + bx * TS;
  const bool tvalid = (tr0 <= ri1) && (tc0 <= rj1);
  int dminB = 0x7fffffff;
  int br = 0, bc = 0;
  if (tvalid) {
    const int te  = (tr0 + TS - 1 < ri1) ? tr0 + TS - 1 : ri1;
    const int tce = (tc0 + TS - 1 < rj1) ? tc0 + TS - 1 : rj1;
    int dr = i0 - te;  if (tr0 - i1 > dr) dr = tr0 - i1; if (dr < 0) dr = 0;
    int dc = j0 - tce; if (tc0 - j1 > dc) dc = tc0 - j1; if (dc < 0) dc = 0;
    dminB = dr > dc ? dr : dc;
    br = tr0 - KS; bc = tc0 - KS;
  }

  // ---- LDS = FINF everywhere (both buffers); rings/pads stay FINF forever
  {
    float* Lf = &L[0][0];
    for (int k = tid; k < 2 * LROWS * LSTR; k += BD) Lf[k] = FINF;
  }

  // ---- strip setup: costs into registers ONCE (persist across all chunks)
  const int srow = tid / NSC, scol = tid - (tid / NSC) * NSC;
  const bool act = tvalid && (tid < NSR * NSC);
  const int r0 = srow * SRB, c0 = scol * SCB;

  float gr[SRB][SCB];
  float cst[SRB][SCB][8];
  bool cin[SRB][SCB];          // in-image predicate per cell
  int  gidx[SRB][SCB];         // global index per cell (valid when cin)
  if (act) {
#pragma unroll
    for (int i = 0; i < SRB; ++i) {
#pragma unroll
      for (int j = 0; j < SCB; ++j) {
        const int wi = r0 + i, wj = c0 + j;
        const int gi2 = br + wi, gj2 = bc + wj;
        const bool inw   = (wi < W2) && (wj < W2);
        const bool inimg = inw && gi2 >= 0 && gi2 < HH && gj2 >= 0 && gj2 < WW;
        cin[i][j] = inimg;
        gidx[i][j] = inimg ? (gi2 * WW + gj2) : 0;
        const int rr = gi2 - ri0, cc = gj2 - rj0;
        const bool inreg = inimg && rr >= 0 && rr < RH && cc >= 0 && cc < RW;
        if (inreg) cost8(ob, yco, xco, gi2, gj2, cst[i][j]);
        else {
#pragma unroll
          for (int d = 0; d < 8; ++d) cst[i][j][d] = BIGC;   // keeps FINF exactly
        }
        gr[i][j] = FINF;
      }
    }
  }

  // ---- strip-level leading-edge distance (global step s first touches at s+1>=ds)
  int ds = 0;
  if (act) {
    const int sr = br + r0, er = br + r0 + SRB - 1;
    const int sc = bc + c0, ec = bc + c0 + SCB - 1;
    int dr = i0 - er; if (sr - i1 > dr) dr = sr - i1; if (dr < 0) dr = 0;
    int dc = j0 - ec; if (sc - j1 > dc) dc = sc - j1; if (dc < 0) dc = 0;
    ds = dr > dc ? dr : dc;
  }

  // image-border replicate flags (cold for harness input)
  const int n0 = -br;
  const int sLast = HH - 1 - br;
  const int w0 = -bc;
  const int eLast = WW - 1 - bc;
  const bool tN = tvalid && (br <= 0), tS = tvalid && (sLast < W2);
  const bool tW = tvalid && (bc <= 0), tE = tvalid && (eLast < W2);
  const bool tAny = tN || tS || tW || tE;

  // ---- chunk loop: read buf[sub&1], write buf[(sub+1)&1]; one grid.sync per chunk
  for (int sub = 0; sub < NSUB; ++sub) {
    const int s0 = sub * KS;
    int s1 = s0 + KS; if (s1 > ns) s1 = ns;
    const int nk = (s1 > s0) ? (s1 - s0) : 0;
    const float* __restrict__ rb = ws_ok ? ((sub & 1) ? wsg : g) : g;
    float* __restrict__       wb = ws_ok ? ((sub & 1) ? g : wsg) : g;
    const bool bact = tvalid && (dminB <= s1);    // block-uniform

    if (bact && act) {
      // reload full working tile from read buffer; publish into L[0]
#pragma unroll
      for (int i = 0; i < SRB; ++i) {
#pragma unroll
        for (int j = 0; j < SCB; ++j) gr[i][j] = cin[i][j] ? rb[gidx[i][j]] : FINF;
        *reinterpret_cast<float4*>(&L[0][(r0 + i + 1) * LSTR + c0 + 4]) =
            make_float4(gr[i][0], gr[i][1], gr[i][2], gr[i][3]);
      }
    }
    __syncthreads();
    if (!ws_ok) grid.sync();   // no ping-pong buffer: separate reads from writes

    if (bact) {
      for (int t = 0; t < nk; ++t) {
        float* __restrict__ Lp = L[t & 1];
        float* __restrict__ Lq = L[(t + 1) & 1];

        if (tAny) {   // replicate-pad refresh on the buffer about to be read
          if (tN) for (int k = tid; k < (n0 + 1) * LSTR; k += BD) {
            const int r = k / LSTR, c = k - r * LSTR;
            Lp[r * LSTR + c] = Lp[(n0 + 1) * LSTR + c];
          }
          if (tS) {
            const int base = sLast + 2, cnt = 51 - base;
            for (int k = tid; k < cnt * LSTR; k += BD) {
              const int r = base + k / LSTR, c = k - (k / LSTR) * LSTR;
              Lp[r * LSTR + c] = Lp[(sLast + 1) * LSTR + c];
            }
          }
          __syncthreads();
          if (tW) {
            const int cn = w0 + 1;
            for (int k = tid; k < 51 * cn; k += BD) {
              const int r = k / cn, c = 3 + (k - (k / cn) * cn);
              Lp[r * LSTR + c] = Lp[r * LSTR + w0 + 4];
            }
          }
          if (tE) {
            const int cbase = eLast + 5, cn = 56 - cbase;
            for (int k = tid; k < 51 * cn; k += BD) {
              const int r = k / cn, c = cbase + (k - (k / cn) * cn);
              Lp[r * LSTR + c] = Lp[r * LSTR + eLast + 4];
            }
          }
          __syncthreads();
        }

        const int sg = s0 + t;
        if (act && (sg + 1 >= ds)) {
          float V[SRB + 2][SCB + 2];
          const float4 qt = *reinterpret_cast<const float4*>(&Lp[(r0) * LSTR + c0 + 4]);
          const float4 qb = *reinterpret_cast<const float4*>(&Lp[(r0 + SRB + 1) * LSTR + c0 + 4]);
          V[0][1] = qt.x; V[0][2] = qt.y; V[0][3] = qt.z; V[0][4] = qt.w;
          V[SRB + 1][1] = qb.x; V[SRB + 1][2] = qb.y; V[SRB + 1][3] = qb.z; V[SRB + 1][4] = qb.w;
#pragma unroll
          for (int i = 0; i < SRB + 2; ++i) {
            V[i][0]       = Lp[(r0 + i) * LSTR + c0 + 3];
            V[i][SCB + 1] = Lp[(r0 + i) * LSTR + c0 + 4 + SCB];
          }
#pragma unroll
          for (int i = 0; i < SRB; ++i)
#pragma unroll
            for (int j = 0; j < SCB; ++j) V[i + 1][j + 1] = gr[i][j];

#pragma unroll
          for (int i = 0; i < SRB; ++i) {
#pragma unroll
            for (int j = 0; j < SCB; ++j) {
              float m = V[i + 1][j + 1];
              m = fminf(m, V[i    ][j    ] + cst[i][j][0]);
              m = fminf(m, V[i + 1][j    ] + cst[i][j][1]);
              m = fminf(m, V[i + 2][j    ] + cst[i][j][2]);
              m = fminf(m, V[i    ][j + 1] + cst[i][j][3]);
              m = fminf(m, V[i + 2][j + 1] + cst[i][j][4]);
              m = fminf(m, V[i    ][j + 2] + cst[i][j][5]);
              m = fminf(m, V[i + 1][j + 2] + cst[i][j][6]);
              m = fminf(m, V[i + 2][j + 2] + cst[i][j][7]);
              gr[i][j] = m;
            }
            *reinterpret_cast<float4*>(&Lq[(r0 + i + 1) * LSTR + c0 + 4]) =
                make_float4(gr[i][0], gr[i][1], gr[i][2], gr[i][3]);
          }
        }
        __syncthreads();
      }

      // write owned cells to write buffer (neighbors read them next chunk)
      if (act) {
#pragma unroll
        for (int i = 0; i < SRB; ++i) {
          const int wi = r0 + i, gi2 = br + wi;
          if (wi >= KS && wi < KS + TS && gi2 <= ri1) {
#pragma unroll
            for (int j = 0; j < SCB; ++j) {
              const int wj = c0 + j, gj2 = bc + wj;
              if (wj >= KS && wj < KS + TS && gj2 <= rj1) wb[gi2 * WW + gj2] = gr[i][j];
            }
          }
        }
      }
    }
    grid.sync();   // all blocks, every chunk: chunk k writes visible before chunk k+1 reads
  }
  // NSUB chunks executed: final state is in buf[NSUB&1] = buf[0] = g when ws_ok.
}

extern "C" void kernel_launch(void* const* d_in, const int* in_sizes, int n_in,
                              void* d_out, int out_size, void* d_ws, size_t ws_size,
                              hipStream_t stream)
{
  const float* ob = (const float*)d_in[0];   // obstacles
  const float* co = (const float*)d_in[1];   // coords (y plane, x plane)
  const float* st = (const float*)d_in[2];   // start_map
  // d_in[3] = goal_map: dead w.r.t. returned g
  const int* nsp  = (const int*)d_in[4];     // num_steps
  float* g = (float*)d_out;

  unsigned int* bb = (unsigned int*)d_ws;
  float* wsg = (float*)((char*)d_ws + 256);
  const int ws_ok = (ws_size >= 256 + (size_t)HH * WW * sizeof(float)) ? 1 : 0;

  k_bbinit<<<1, 64, 0, stream>>>(bb);
  k_init<<<(HH * WW / 4) / 256, 256, 0, stream>>>(st, g, bb, wsg, ws_ok);

  void* args[7];
  args[0] = (void*)&ob;  args[1] = (void*)&co;  args[2] = (void*)&bb;
  args[3] = (void*)&g;   args[4] = (void*)&nsp; args[5] = (void*)&wsg;
  args[6] = (void*)&ws_ok;
  hipLaunchCooperativeKernel((void*)k_coop, dim3(NBLK), dim3(BD), args, 0, stream);
}

// Round 6
// 161.653 us; speedup vs baseline: 1.0876x; 1.0876x over previous
//
#include <hip/hip_runtime.h>
#include <hip/hip_cooperative_groups.h>
#include <cstdint>

namespace cg = cooperative_groups;

// DifferentiableStarPlanner, MI355X — round 6.
// R5 post-mortem: VGPR_Count=68 on k_coop => the per-thread cst[2][4][8] array
// spilled to scratch AGAIN (same as R2). Two data points: hipcc won't keep big
// per-thread arrays in VGPRs here (SROA failure via cost8(float*) and/or spills
// around grid.sync call boundaries). Fix: costs live in LDS (spill-proof),
// computed once per block; per-thread state = f32x4 gr + 8 f32x4 cost vectors
// reloaded per CHUNK (spill damage bounded even if allocator misbehaves).
// Also: 64 blocks (8x8 tiles, TS=17, KS=16, NSUB=4) -> grid.syncs 8->4, and
// 4x the CUs. Trapezoid overlap redundancy is paid in idle-CU compute.
//
// Exactness: min-plus relaxation, propagation <=1 cell/step; ring cells frozen
// at chunk-start values are >= true values (monotone decrease), contamination
// moves <=1 cell/step inward, owned cells are KS=16 layers deep. Strips that
// were never active hold FINF in BOTH LDS buffers (init fill), matching their
// true value g_init=FINF (skip guarantee). Chunks with nk==0 copy rb->wb so the
// final result always lands in g after NSUB chunks.

#define HH 1024
#define WW 1024
#define FINF 1.0e7f
#define FOB  1.0e4f
#define FEPS 1e-12f
#define BIGC 1.0e30f

#define TS   17               // owned tile edge; 8x8 tiles
#define KS   16               // steps per chunk = halo width
#define NSUB 4                // KS*NSUB = 64 steps max on tiled path
#define W2   (TS + 2*KS)      // 49: working tile edge
#define MAXR 136              // 8*TS >= 2*64+1 = 129
#define LROWS 52              // g-buffer rows: ring+working(49)+ring+pad
#define LSTR  60              // g-buffer row stride (floats); reads reach col 56
#define CPL   52              // cost plane row stride (floats), cols 0..51
#define NSC 13                // col strips per row (ceil(49/4))
#define NACT (W2 * NSC)       // 637 active threads
#define BD  640               // 10 waves
#define NBLK 64

typedef __attribute__((ext_vector_type(4))) float f32x4;

// -------- per-cell, per-direction path costs (exact port of calculateLocalPathCosts)
__device__ __forceinline__ void cost8(const float* __restrict__ ob,
                                      const float* __restrict__ yco,
                                      const float* __restrict__ xco,
                                      int gi, int gj, float c[8])
{
  const int jm = gj > 0      ? gj - 1 : 0;
  const int jp = gj < WW - 1 ? gj + 1 : WW - 1;
  const int im = gi > 0      ? gi - 1 : 0;
  const int ip = gi < HH - 1 ? gi + 1 : HH - 1;
  const float xc = xco[gi * WW + gj];
  const float yc = yco[gi * WW + gj];
  const float dl = xc - xco[gi * WW + jm]; const float l = dl * dl;
  const float dr = xc - xco[gi * WW + jp]; const float r = dr * dr;
  const float du = yc - yco[im * WW + gj]; const float u = du * du;
  const float dd = yc - yco[ip * WW + gj]; const float d = dd * dd;
  const float oc  = ob[gi * WW + gj];
  const float oNW = ob[im * WW + jm], oN = ob[im * WW + gj], oNE = ob[im * WW + jp];
  const float oE  = ob[gi * WW + jp];
  const float oSW = ob[ip * WW + jm], oS = ob[ip * WW + gj], oSE = ob[ip * WW + jp];
  // dir order: 0 NW(-1,-1) 1 W(0,-1) 2 SW(1,-1) 3 N(-1,0) 4 S(1,0) 5 NE(-1,1) 6 E(0,1) 7 SE(1,1)
  c[0] = sqrtf(l + u + FEPS) + FOB * fmaxf(oNW, oc);
  c[1] = sqrtf(l + FEPS)     + FOB * fmaxf(oN , oc);  // reference quirk: W move uses N obstacle
  c[2] = sqrtf(l + d + FEPS) + FOB * fmaxf(oSW, oc);
  c[3] = sqrtf(u + FEPS)     + FOB * fmaxf(oN , oc);
  c[4] = sqrtf(d + FEPS)     + FOB * fmaxf(oS , oc);
  c[5] = sqrtf(r + u + FEPS) + FOB * fmaxf(oNE, oc);
  c[6] = sqrtf(r + FEPS)     + FOB * fmaxf(oE , oc);
  c[7] = sqrtf(r + d + FEPS) + FOB * fmaxf(oSE, oc);
}

__device__ __forceinline__ bool region_of(const unsigned* __restrict__ bb, int ns,
                                          int& i0, int& i1, int& j0, int& j1,
                                          int& ri0, int& ri1, int& rj0, int& rj1,
                                          int& RH, int& RW)
{
  if (bb[0] > (unsigned)(HH - 1)) return false;
  i0 = (int)bb[0]; i1 = 4096 - (int)bb[1];
  j0 = (int)bb[2]; j1 = 4096 - (int)bb[3];
  ri0 = i0 - ns; if (ri0 < 0) ri0 = 0;
  ri1 = i1 + ns; if (ri1 > HH - 1) ri1 = HH - 1;
  rj0 = j0 - ns; if (rj0 < 0) rj0 = 0;
  rj1 = j1 + ns; if (rj1 > WW - 1) rj1 = WW - 1;
  RH = ri1 - ri0 + 1; RW = rj1 - rj0 + 1;
  return true;
}

// -------- K0: bbox init (ws re-poisoned every call)
__global__ void k_bbinit(unsigned int* bb)
{
  if (threadIdx.x < 4) bb[threadIdx.x] = 0xFFFFFFFFu;
}

// -------- K1: g_init into BOTH ping-pong buffers + start bbox via atomicMin
__global__ void k_init(const float* __restrict__ start, float* __restrict__ g,
                       unsigned int* bb, float* __restrict__ wsg, int ws_ok)
{
  const int idx = blockIdx.x * blockDim.x + threadIdx.x;     // over H*W/4
  const float4 s = reinterpret_cast<const float4*>(start)[idx];
  float4 o;
  o.x = fminf(fmaxf(FINF * (1.0f - s.x), 0.0f), FINF);
  o.y = fminf(fmaxf(FINF * (1.0f - s.y), 0.0f), FINF);
  o.z = fminf(fmaxf(FINF * (1.0f - s.z), 0.0f), FINF);
  o.w = fminf(fmaxf(FINF * (1.0f - s.w), 0.0f), FINF);
  reinterpret_cast<float4*>(g)[idx] = o;
  if (ws_ok) reinterpret_cast<float4*>(wsg)[idx] = o;
  if (s.x > 0.0f || s.y > 0.0f || s.z > 0.0f || s.w > 0.0f) {
    const int base = idx * 4;
    const int r  = base >> 10;
    const int c0 = base & (WW - 1);
    atomicMin(bb + 0, (unsigned)r);
    atomicMin(bb + 1, (unsigned)(4096 - r));
    if (s.x > 0.0f) { atomicMin(bb + 2, (unsigned)(c0 + 0)); atomicMin(bb + 3, (unsigned)(4096 - (c0 + 0))); }
    if (s.y > 0.0f) { atomicMin(bb + 2, (unsigned)(c0 + 1)); atomicMin(bb + 3, (unsigned)(4096 - (c0 + 1))); }
    if (s.z > 0.0f) { atomicMin(bb + 2, (unsigned)(c0 + 2)); atomicMin(bb + 3, (unsigned)(4096 - (c0 + 2))); }
    if (s.w > 0.0f) { atomicMin(bb + 2, (unsigned)(c0 + 3)); atomicMin(bb + 3, (unsigned)(4096 - (c0 + 3))); }
  }
}

// -------- K2: single cooperative kernel, NSUB chunks, costs in LDS
__global__ __launch_bounds__(BD, 2) void k_coop(
    const float* __restrict__ ob, const float* __restrict__ co,
    const unsigned* __restrict__ bb, float* __restrict__ g,
    const int* __restrict__ nsp, float* __restrict__ wsg, int ws_ok)
{
  cg::grid_group grid = cg::this_grid();
  __shared__ float Lg[2][LROWS * LSTR];   // g double-buffer  (24.96 KB)
  __shared__ float Lc[8][W2 * CPL];       // cost planes [dir][row][col] (81.5 KB)
  const float* yco = co;
  const float* xco = co + HH * WW;
  const int tid = threadIdx.x;

  int ns = *nsp; if (ns < 0) ns = 0;
  int i0,i1,j0,j1, ri0,ri1,rj0,rj1, RH,RW;
  if (!region_of(bb, ns, i0,i1,j0,j1, ri0,ri1,rj0,rj1, RH,RW)) return;  // grid-uniform

  // ---- defensive fallback (never triggered by harness input): global Jacobi
  if (ns > KS * NSUB || RH > MAXR || RW > MAXR) {                        // grid-uniform
    if (!ws_ok) return;
    const int gt = blockIdx.x * BD + tid, nthr = NBLK * BD;
    for (int s = 0; s < ns; ++s) {
      const float* src = (s & 1) ? wsg : g;
      float*       dst = (s & 1) ? g : wsg;
      for (int k = gt; k < HH * WW; k += nthr) {
        const int gi = k >> 10, gj = k & (WW - 1);
        float c[8]; cost8(ob, yco, xco, gi, gj, c);
        const int im = gi > 0 ? gi - 1 : 0, ip = gi < HH - 1 ? gi + 1 : HH - 1;
        const int jm = gj > 0 ? gj - 1 : 0, jp = gj < WW - 1 ? gj + 1 : WW - 1;
        float m = src[k];
        m = fminf(m, src[im * WW + jm] + c[0]); m = fminf(m, src[gi * WW + jm] + c[1]);
        m = fminf(m, src[ip * WW + jm] + c[2]); m = fminf(m, src[im * WW + gj] + c[3]);
        m = fminf(m, src[ip * WW + gj] + c[4]); m = fminf(m, src[im * WW + jp] + c[5]);
        m = fminf(m, src[gi * WW + jp] + c[6]); m = fminf(m, src[ip * WW + jp] + c[7]);
        dst[k] = m;
      }
      grid.sync();
    }
    if (ns & 1) { for (int k = gt; k < HH * WW; k += nthr) g[k] = wsg[k]; }
    return;
  }

  // ---- tile geometry (8x8 tiles of TS over the region)
  const int by = blockIdx.x >> 3, bx = blockIdx.x & 7;
  const int tr0 = ri0 + by * TS, tc0 = rj0 + bx * TS;
  const bool tvalid = (tr0 <= ri1) && (tc0 <= rj1);
  int dminB = 0x7fffffff;
  int br = 0, bc = 0;
  if (tvalid) {
    const int te  = (tr0 + TS - 1 < ri1) ? tr0 + TS - 1 : ri1;
    const int tce = (tc0 + TS - 1 < rj1) ? tc0 + TS - 1 : rj1;
    int dr = i0 - te;  if (tr0 - i1 > dr) dr = tr0 - i1; if (dr < 0) dr = 0;
    int dc = j0 - tce; if (tc0 - j1 > dc) dc = tc0 - j1; if (dc < 0) dc = 0;
    dminB = dr > dc ? dr : dc;
    br = tr0 - KS; bc = tc0 - KS;
  }

  // ---- LDS g-buffers = FINF everywhere (rings/pads stay FINF unless replicated)
  {
    float* Lf = &Lg[0][0];
    for (int k = tid; k < 2 * LROWS * LSTR; k += BD) Lf[k] = FINF;
  }

  // ---- fill cost planes once (incl. BIGC pad cols 49..51)
  if (tvalid) {
    for (int cell = tid; cell < W2 * CPL; cell += BD) {
      const int wi = cell / CPL, wj = cell - wi * CPL;
      const int gi = br + wi, gj = bc + wj;
      const int rr = gi - ri0, cc = gj - rj0;
      float c8[8];
      if (wj < W2 && rr >= 0 && rr < RH && cc >= 0 && cc < RW) {
        cost8(ob, yco, xco, gi, gj, c8);
      } else {
#pragma unroll
        for (int d = 0; d < 8; ++d) c8[d] = BIGC;   // keeps out-of-region cells at FINF
      }
#pragma unroll
      for (int d = 0; d < 8; ++d) Lc[d][wi * CPL + wj] = c8[d];
    }
  }
  __syncthreads();

  // ---- strip: 1 row x 4 cols per thread
  const int wi = tid / NSC;
  const int c0 = (tid - wi * NSC) * 4;
  const bool act = tvalid && (tid < NACT);

  // strip-level leading-edge distance (step s touches cell iff s+1 >= dist)
  int ds = 0;
  if (act) {
    const int sr = br + wi;
    const int sc = bc + c0, ec = bc + c0 + 3;
    int dr = i0 - sr; if (sr - i1 > dr) dr = sr - i1; if (dr < 0) dr = 0;
    int dc = j0 - ec; if (sc - j1 > dc) dc = sc - j1; if (dc < 0) dc = 0;
    ds = dr > dc ? dr : dc;
  }

  // image-border replicate flags (cold: harness region is interior)
  const int n0 = -br;                  // # out-of-image rows above (if tN)
  const int sLast = HH - 1 - br;       // working-row index of image row HH-1
  const int w0 = -bc;
  const int eLast = WW - 1 - bc;
  const bool tN = tvalid && (br <= 0), tS = tvalid && (sLast < W2);
  const bool tW = tvalid && (bc <= 0), tE = tvalid && (eLast < W2);
  const bool tAny = tN || tS || tW || tE;

  // ---- chunk loop: read buf[sub&1], write buf[(sub+1)&1]; 1 grid.sync per chunk
  for (int sub = 0; sub < NSUB; ++sub) {
    const int s0 = sub * KS;
    int s1 = s0 + KS; if (s1 > ns) s1 = ns;
    const int nk = (s1 > s0) ? (s1 - s0) : 0;     // nk==0 -> pure copy chunk
    const float* __restrict__ rb = ws_ok ? ((sub & 1) ? wsg : g) : g;
    float* __restrict__       wb = ws_ok ? ((sub & 1) ? g : wsg) : g;
    const bool bact = tvalid && (dminB <= s1);    // block-uniform

    f32x4 gr;
    gr[0] = FINF; gr[1] = FINF; gr[2] = FINF; gr[3] = FINF;
    if (bact && act) {
      // reload working cells from read buffer; publish into Lg[0]
      const int gi = br + wi;
#pragma unroll
      for (int j = 0; j < 4; ++j) {
        const int gj = bc + c0 + j;
        if (gi >= 0 && gi < HH && gj >= 0 && gj < WW) gr[j] = rb[gi * WW + gj];
      }
      *reinterpret_cast<f32x4*>(&Lg[0][(wi + 1) * LSTR + c0 + 4]) = gr;
    }
    __syncthreads();
    if (!ws_ok) grid.sync();   // no ping-pong buffer: separate all reads from writes

    if (bact) {
      // per-chunk cost vectors into registers (from LDS; bounded damage if spilled)
      f32x4 cd0, cd1, cd2, cd3, cd4, cd5, cd6, cd7;
      if (act) {
        const int cb = wi * CPL + c0;
        cd0 = *reinterpret_cast<const f32x4*>(&Lc[0][cb]);
        cd1 = *reinterpret_cast<const f32x4*>(&Lc[1][cb]);
        cd2 = *reinterpret_cast<const f32x4*>(&Lc[2][cb]);
        cd3 = *reinterpret_cast<const f32x4*>(&Lc[3][cb]);
        cd4 = *reinterpret_cast<const f32x4*>(&Lc[4][cb]);
        cd5 = *reinterpret_cast<const f32x4*>(&Lc[5][cb]);
        cd6 = *reinterpret_cast<const f32x4*>(&Lc[6][cb]);
        cd7 = *reinterpret_cast<const f32x4*>(&Lc[7][cb]);
      }

      for (int t = 0; t < nk; ++t) {
        float* __restrict__ Lp = Lg[t & 1];
        float* __restrict__ Lq = Lg[(t + 1) & 1];

        if (tAny) {   // replicate-pad refresh on the buffer about to be read
          if (tN) for (int k = tid; k < (n0 + 1) * LSTR; k += BD) {
            const int r = k / LSTR, c = k - r * LSTR;
            Lp[r * LSTR + c] = Lp[(n0 + 1) * LSTR + c];
          }
          if (tS) {
            const int base = sLast + 2, cnt = (LROWS - 1) - base;   // rows base..50
            for (int k = tid; k < cnt * LSTR; k += BD) {
              const int r = base + k / LSTR, c = k - (k / LSTR) * LSTR;
              Lp[r * LSTR + c] = Lp[(sLast + 1) * LSTR + c];
            }
          }
          __syncthreads();
          if (tW) {
            const int cn = w0 + 1;                  // cols 3..w0+3, all rows 0..50
            for (int k = tid; k < (LROWS - 1) * cn; k += BD) {
              const int r = k / cn, c = 3 + (k - (k / cn) * cn);
              Lp[r * LSTR + c] = Lp[r * LSTR + w0 + 4];
            }
          }
          if (tE) {
            const int cbase = eLast + 5, cn = 58 - cbase;  // cols cbase..57
            for (int k = tid; k < (LROWS - 1) * cn; k += BD) {
              const int r = k / cn, c = cbase + (k - (k / cn) * cn);
              Lp[r * LSTR + c] = Lp[r * LSTR + eLast + 4];
            }
          }
          __syncthreads();
        }

        const int sg = s0 + t;
        if (act && (sg + 1 >= ds)) {
          // V rows: above/own/below, cols c0-1 .. c0+4
          float V0[6], V1[6], V2[6];
          const f32x4 a = *reinterpret_cast<const f32x4*>(&Lp[(wi    ) * LSTR + c0 + 4]);
          const f32x4 b = *reinterpret_cast<const f32x4*>(&Lp[(wi + 2) * LSTR + c0 + 4]);
          V0[1] = a[0]; V0[2] = a[1]; V0[3] = a[2]; V0[4] = a[3];
          V2[1] = b[0]; V2[2] = b[1]; V2[3] = b[2]; V2[4] = b[3];
          V0[0] = Lp[(wi    ) * LSTR + c0 + 3];  V0[5] = Lp[(wi    ) * LSTR + c0 + 8];
          V1[0] = Lp[(wi + 1) * LSTR + c0 + 3];  V1[5] = Lp[(wi + 1) * LSTR + c0 + 8];
          V2[0] = Lp[(wi + 2) * LSTR + c0 + 3];  V2[5] = Lp[(wi + 2) * LSTR + c0 + 8];
          V1[1] = gr[0]; V1[2] = gr[1]; V1[3] = gr[2]; V1[4] = gr[3];

#define UPD(j) do { float m = gr[j];                    \
            m = fminf(m, V0[j]     + cd0[j]);           \
            m = fminf(m, V1[j]     + cd1[j]);           \
            m = fminf(m, V2[j]     + cd2[j]);           \
            m = fminf(m, V0[j + 1] + cd3[j]);           \
            m = fminf(m, V2[j + 1] + cd4[j]);           \
            m = fminf(m, V0[j + 2] + cd5[j]);           \
            m = fminf(m, V1[j + 2] + cd6[j]);           \
            m = fminf(m, V2[j + 2] + cd7[j]);           \
            gr[j] = m; } while (0)
          UPD(0); UPD(1); UPD(2); UPD(3);
#undef UPD
          *reinterpret_cast<f32x4*>(&Lq[(wi + 1) * LSTR + c0 + 4]) = gr;
        }
        __syncthreads();
      }

      // writeback owned cells (wi,wj in [KS, KS+TS), clamped to region)
      if (act && wi >= KS && wi < KS + TS) {
        const int gi = br + wi;
        if (gi <= ri1) {
#pragma unroll
          for (int j = 0; j < 4; ++j) {
            const int wj = c0 + j, gj = bc + wj;
            if (wj >= KS && wj < KS + TS && gj <= rj1) wb[gi * WW + gj] = gr[j];
          }
        }
      }
    }
    grid.sync();   // chunk writes visible before next chunk reads
  }
  // NSUB=4 chunks (working or copy) executed: final state is in buf[0] = g.
}

extern "C" void kernel_launch(void* const* d_in, const int* in_sizes, int n_in,
                              void* d_out, int out_size, void* d_ws, size_t ws_size,
                              hipStream_t stream)
{
  const float* ob = (const float*)d_in[0];   // obstacles
  const float* co = (const float*)d_in[1];   // coords (y plane, x plane)
  const float* st = (const float*)d_in[2];   // start_map
  // d_in[3] = goal_map: dead w.r.t. returned g
  const int* nsp  = (const int*)d_in[4];     // num_steps
  float* g = (float*)d_out;

  unsigned int* bb = (unsigned int*)d_ws;
  float* wsg = (float*)((char*)d_ws + 256);
  const int ws_ok = (ws_size >= 256 + (size_t)HH * WW * sizeof(float)) ? 1 : 0;

  k_bbinit<<<1, 64, 0, stream>>>(bb);
  k_init<<<(HH * WW / 4) / 256, 256, 0, stream>>>(st, g, bb, wsg, ws_ok);

  void* args[7];
  args[0] = (void*)&ob;  args[1] = (void*)&co;  args[2] = (void*)&bb;
  args[3] = (void*)&g;   args[4] = (void*)&nsp; args[5] = (void*)&wsg;
  args[6] = (void*)&ws_ok;
  hipLaunchCooperativeKernel((void*)k_coop, dim3(NBLK), dim3(BD), args, 0, stream);
}

// Round 8
// 159.292 us; speedup vs baseline: 1.1037x; 1.0148x over previous
//
#include <hip/hip_runtime.h>
#include <hip/hip_cooperative_groups.h>
#include <cstdint>

namespace cg = cooperative_groups;

// DifferentiableStarPlanner, MI355X — round 7 resubmit (R7 bench never acquired a GPU).
// R6 post-mortem: k_coop 65us (spill-free, structure-bound: ~29us step-LDS +
// syncs/fill), plus ~96us outside the kernel (k_init, k_bbinit, launch gaps,
// harness fill). This round:
//  - Everything in one cooperative kernel: phase A = g_init + per-block bbox
//    slice (no atomics-init problem), grid.sync, slice-reduce, then 4 chunks.
//  - Ping-pong via two compact 136x136 region buffers in ws. Chunk 0 synthesizes
//    g0 from start_map; later chunks read FINF for cells with
//    chebyshev-dist(start bbox) > s0 (exact: min-plus moves info <=1 cell/step,
//    and such cells' owners provably wrote the buffer otherwise). Buffers need
//    NO init.
//  - 2x4-cell strips (own rows in regs): per-step LDS ~half of R6's 1x4 layout.
// Exactness unchanged: trapezoidal halo KS=16 per chunk, owned cells 16 deep;
// stale ring values are >= true (monotone), contamination <=1 cell/step.

#define HH 1024
#define WW 1024
#define FINF 1.0e7f
#define FOB  1.0e4f
#define FEPS 1e-12f
#define BIGC 1.0e30f

#define TS   17               // owned tile edge; 8x8 tiles
#define KS   16               // steps per chunk = halo width
#define NSUB 4                // KS*NSUB = 64 steps max on tiled path
#define W2   (TS + 2*KS)      // 49: working tile edge
#define MAXR 136              // 8*TS = 136 >= 2*64+1
#define RSTR 136              // compact region buffer stride
#define LROWS 52              // Lg rows: ring + working(49) + ring + pad
#define LSTR  60              // Lg row stride (floats)
#define CPL   52              // cost plane stride (floats)
#define NSC 13                // col strips (ceil(49/4))
#define TROWS 25              // row strips (ceil(49/2))
#define NACT (TROWS * NSC)    // 325 active threads in step loop
#define BD  512               // 8 waves
#define NBLK 64

typedef __attribute__((ext_vector_type(4))) float f32x4;

// -------- per-cell, per-direction path costs (exact port of calculateLocalPathCosts)
__device__ __forceinline__ void cost8(const float* __restrict__ ob,
                                      const float* __restrict__ yco,
                                      const float* __restrict__ xco,
                                      int gi, int gj, float c[8])
{
  const int jm = gj > 0      ? gj - 1 : 0;
  const int jp = gj < WW - 1 ? gj + 1 : WW - 1;
  const int im = gi > 0      ? gi - 1 : 0;
  const int ip = gi < HH - 1 ? gi + 1 : HH - 1;
  const float xc = xco[gi * WW + gj];
  const float yc = yco[gi * WW + gj];
  const float dl = xc - xco[gi * WW + jm]; const float l = dl * dl;
  const float dr = xc - xco[gi * WW + jp]; const float r = dr * dr;
  const float du = yc - yco[im * WW + gj]; const float u = du * du;
  const float dd = yc - yco[ip * WW + gj]; const float d = dd * dd;
  const float oc  = ob[gi * WW + gj];
  const float oNW = ob[im * WW + jm], oN = ob[im * WW + gj], oNE = ob[im * WW + jp];
  const float oE  = ob[gi * WW + jp];
  const float oSW = ob[ip * WW + jm], oS = ob[ip * WW + gj], oSE = ob[ip * WW + jp];
  // dir order: 0 NW(-1,-1) 1 W(0,-1) 2 SW(1,-1) 3 N(-1,0) 4 S(1,0) 5 NE(-1,1) 6 E(0,1) 7 SE(1,1)
  c[0] = sqrtf(l + u + FEPS) + FOB * fmaxf(oNW, oc);
  c[1] = sqrtf(l + FEPS)     + FOB * fmaxf(oN , oc);  // reference quirk: W move uses N obstacle
  c[2] = sqrtf(l + d + FEPS) + FOB * fmaxf(oSW, oc);
  c[3] = sqrtf(u + FEPS)     + FOB * fmaxf(oN , oc);
  c[4] = sqrtf(d + FEPS)     + FOB * fmaxf(oS , oc);
  c[5] = sqrtf(r + u + FEPS) + FOB * fmaxf(oNE, oc);
  c[6] = sqrtf(r + FEPS)     + FOB * fmaxf(oE , oc);
  c[7] = sqrtf(r + d + FEPS) + FOB * fmaxf(oSE, oc);
}

// value of cell (gi,gj) at the start of chunk `sub` (global step s0)
__device__ __forceinline__ float load_cell(int sub, int gi, int gj, int s0,
                                           const float* __restrict__ rbuf,
                                           const float* __restrict__ start,
                                           int i0, int i1, int j0, int j1,
                                           int ri0, int rj0)
{
  if (gi < 0 || gi >= HH || gj < 0 || gj >= WW) return FINF;
  if (sub == 0) {
    const float s = start[gi * WW + gj];
    return fminf(fmaxf(FINF * (1.0f - s), 0.0f), FINF);
  }
  int dr = i0 - gi; { const int t2 = gi - i1; if (t2 > dr) dr = t2; } if (dr < 0) dr = 0;
  int dc = j0 - gj; { const int t2 = gj - j1; if (t2 > dc) dc = t2; } if (dc < 0) dc = 0;
  const int dist = dr > dc ? dr : dc;
  if (dist > s0) return FINF;                       // provably unchanged => g_init (FINF)
  return rbuf[(gi - ri0) * RSTR + (gj - rj0)];      // owner provably wrote last chunk
}

// -------- THE kernel: init + bbox + costs + 64 relaxation steps, one dispatch
__global__ __launch_bounds__(BD, 2) void k_all(
    const float* __restrict__ ob, const float* __restrict__ co,
    const float* __restrict__ start, float* __restrict__ g,
    const int* __restrict__ nsp, unsigned* __restrict__ bbslice,
    float* __restrict__ bufA, float* __restrict__ bufB,
    float* __restrict__ wsg, int ws_ok)
{
  cg::grid_group grid = cg::this_grid();
  __shared__ float Lg[2][LROWS * LSTR];   // g double-buffer (24.96 KB)
  __shared__ float Lc[8][W2 * CPL];       // cost planes (81.5 KB)
  __shared__ unsigned sred[4];
  const float* yco = co;
  const float* xco = co + HH * WW;
  const int tid = threadIdx.x;
  int ns = *nsp; if (ns < 0) ns = 0;

  // ================= phase A: g_init (whole image) + per-block bbox slice
  {
    unsigned lminr = 0xFFFFFFFFu, lmaxr = 0u, lminc = 0xFFFFFFFFu, lmaxc = 0u;
    const int base_f4 = blockIdx.x * 4096;          // 64 blocks x 4096 f4 = H*W/4
#pragma unroll
    for (int i = 0; i < 8; ++i) {
      const int idx = base_f4 + tid + i * BD;
      const float4 s = reinterpret_cast<const float4*>(start)[idx];
      float4 o;
      o.x = fminf(fmaxf(FINF * (1.0f - s.x), 0.0f), FINF);
      o.y = fminf(fmaxf(FINF * (1.0f - s.y), 0.0f), FINF);
      o.z = fminf(fmaxf(FINF * (1.0f - s.z), 0.0f), FINF);
      o.w = fminf(fmaxf(FINF * (1.0f - s.w), 0.0f), FINF);
      reinterpret_cast<float4*>(g)[idx] = o;
      if (s.x > 0.0f || s.y > 0.0f || s.z > 0.0f || s.w > 0.0f) {
        const int cb = idx * 4;
        const unsigned r = (unsigned)(cb >> 10), c = (unsigned)(cb & 1023);
        if (r < lminr) lminr = r;
        if (r > lmaxr) lmaxr = r;
        if (s.x > 0.0f) { if (c     < lminc) lminc = c;     if (c     > lmaxc) lmaxc = c;     }
        if (s.y > 0.0f) { if (c + 1 < lminc) lminc = c + 1; if (c + 1 > lmaxc) lmaxc = c + 1; }
        if (s.z > 0.0f) { if (c + 2 < lminc) lminc = c + 2; if (c + 2 > lmaxc) lmaxc = c + 2; }
        if (s.w > 0.0f) { if (c + 3 < lminc) lminc = c + 3; if (c + 3 > lmaxc) lmaxc = c + 3; }
      }
    }
    if (tid == 0) { sred[0] = 0xFFFFFFFFu; sred[1] = 0u; sred[2] = 0xFFFFFFFFu; sred[3] = 0u; }
    __syncthreads();
    if (lminr != 0xFFFFFFFFu) {
      atomicMin(&sred[0], lminr); atomicMax(&sred[1], lmaxr);
      atomicMin(&sred[2], lminc); atomicMax(&sred[3], lmaxc);
    }
    __syncthreads();
    if (tid < 4) bbslice[blockIdx.x * 4 + tid] = sred[tid];
  }
  grid.sync();

  // ================= bbox reduce (64 slices; race-free, no init dependence)
  {
    if (tid == 0) { sred[0] = 0xFFFFFFFFu; sred[1] = 0u; sred[2] = 0xFFFFFFFFu; sred[3] = 0u; }
    __syncthreads();
    if (tid < NBLK) {
      const uint4 sl = reinterpret_cast<const uint4*>(bbslice)[tid];
      if (sl.x != 0xFFFFFFFFu) {
        atomicMin(&sred[0], sl.x); atomicMax(&sred[1], sl.y);
        atomicMin(&sred[2], sl.z); atomicMax(&sred[3], sl.w);
      }
    }
    __syncthreads();
  }
  if (sred[0] == 0xFFFFFFFFu) return;               // no start cells: g = g_init, done
  const int i0 = (int)sred[0], i1 = (int)sred[1];
  const int j0 = (int)sred[2], j1 = (int)sred[3];

  int ri0 = i0 - ns; if (ri0 < 0) ri0 = 0;
  int ri1 = i1 + ns; if (ri1 > HH - 1) ri1 = HH - 1;
  int rj0 = j0 - ns; if (rj0 < 0) rj0 = 0;
  int rj1 = j1 + ns; if (rj1 > WW - 1) rj1 = WW - 1;
  const int RH = ri1 - ri0 + 1, RW = rj1 - rj0 + 1;

  // ================= defensive fallback (unreachable for harness input)
  if (ns > KS * NSUB || RH > MAXR || RW > MAXR) {
    if (!ws_ok) return;
    const int gt = blockIdx.x * BD + tid, nthr = NBLK * BD;
    for (int s = 0; s < ns; ++s) {
      const float* src = (s & 1) ? wsg : g;
      float*       dst = (s & 1) ? g : wsg;
      for (int k = gt; k < HH * WW; k += nthr) {
        const int gi = k >> 10, gj = k & (WW - 1);
        float c[8]; cost8(ob, yco, xco, gi, gj, c);
        const int im = gi > 0 ? gi - 1 : 0, ip = gi < HH - 1 ? gi + 1 : HH - 1;
        const int jm = gj > 0 ? gj - 1 : 0, jp = gj < WW - 1 ? gj + 1 : WW - 1;
        float m = src[k];
        m = fminf(m, src[im * WW + jm] + c[0]); m = fminf(m, src[gi * WW + jm] + c[1]);
        m = fminf(m, src[ip * WW + jm] + c[2]); m = fminf(m, src[im * WW + gj] + c[3]);
        m = fminf(m, src[ip * WW + gj] + c[4]); m = fminf(m, src[im * WW + jp] + c[5]);
        m = fminf(m, src[gi * WW + jp] + c[6]); m = fminf(m, src[ip * WW + jp] + c[7]);
        dst[k] = m;
      }
      grid.sync();
    }
    if (ns & 1) { for (int k = gt; k < HH * WW; k += nthr) g[k] = wsg[k]; }
    return;
  }
  if (ns == 0) return;                               // g = g_init, done

  // ================= tile geometry (8x8 tiles of TS)
  const int by = blockIdx.x >> 3, bx = blockIdx.x & 7;
  const int tr0 = ri0 + by * TS, tc0 = rj0 + bx * TS;
  const bool tvalid = (tr0 <= ri1) && (tc0 <= rj1);
  int dminB = 0x7fffffff;
  int br = 0, bc = 0;
  if (tvalid) {
    const int te  = (tr0 + TS - 1 < ri1) ? tr0 + TS - 1 : ri1;
    const int tce = (tc0 + TS - 1 < rj1) ? tc0 + TS - 1 : rj1;
    int dr = i0 - te;  if (tr0 - i1 > dr) dr = tr0 - i1; if (dr < 0) dr = 0;
    int dc = j0 - tce; if (tc0 - j1 > dc) dc = tc0 - j1; if (dc < 0) dc = 0;
    dminB = dr > dc ? dr : dc;
    br = tr0 - KS; bc = tc0 - KS;
  }

  // ================= LDS: g-buffers = FINF; cost planes
  {
    float* Lf = &Lg[0][0];
    for (int k = tid; k < 2 * LROWS * LSTR; k += BD) Lf[k] = FINF;
  }
  if (tvalid) {
    for (int cell = tid; cell < W2 * CPL; cell += BD) {
      const int wi = cell / CPL, wj = cell - wi * CPL;
      const int gi = br + wi, gj = bc + wj;
      const int rr = gi - ri0, cc = gj - rj0;
      float c8[8];
      if (wj < W2 && rr >= 0 && rr < RH && cc >= 0 && cc < RW) {
        cost8(ob, yco, xco, gi, gj, c8);
      } else {
#pragma unroll
        for (int d = 0; d < 8; ++d) c8[d] = BIGC;
      }
#pragma unroll
      for (int d = 0; d < 8; ++d) Lc[d][wi * CPL + wj] = c8[d];
    }
  }
  __syncthreads();

  // ================= strip: 2 rows x 4 cols per thread
  const int trow = tid / NSC;
  const int c0 = (tid - trow * NSC) * 4;
  const bool act = tvalid && (tid < NACT);
  const int wA = 2 * trow, wB = wA + 1;
  const bool rowBok = (wB < W2);

  int ds = 0;
  if (act) {
    const int sr = br + wA, er = br + (rowBok ? wB : wA);
    const int sc = bc + c0, ec = bc + c0 + 3;
    int dr = i0 - er; if (sr - i1 > dr) dr = sr - i1; if (dr < 0) dr = 0;
    int dc = j0 - ec; if (sc - j1 > dc) dc = sc - j1; if (dc < 0) dc = 0;
    ds = dr > dc ? dr : dc;
  }

  // image-border replicate flags (cold: harness region is interior)
  const int n0 = -br;
  const int sLast = HH - 1 - br;
  const int w0 = -bc;
  const int eLast = WW - 1 - bc;
  const bool tN = tvalid && (br <= 0), tS = tvalid && (sLast < W2);
  const bool tW = tvalid && (bc <= 0), tE = tvalid && (eLast < W2);
  const bool tAny = tN || tS || tW || tE;

  // ================= chunk loop
  const int L = (ns + KS - 1) / KS - 1;              // last chunk index (ns>=1)
  for (int sub = 0; sub <= L; ++sub) {
    const int s0 = sub * KS;
    const int s1 = (s0 + KS < ns) ? s0 + KS : ns;
    const int nk = s1 - s0;
    const bool lastC = (sub == L);
    const float* __restrict__ rbuf = (sub & 1) ? bufA : bufB;   // read: prev chunk's write
    float* __restrict__       wbuf = (sub & 1) ? bufB : bufA;   // write (non-last chunks)
    const bool bact = tvalid && (dminB <= s1);                  // block-uniform

    f32x4 grA; grA[0] = FINF; grA[1] = FINF; grA[2] = FINF; grA[3] = FINF;
    f32x4 grB = grA;
    if (bact && act) {
      const int giA = br + wA, giB = br + wB;
#pragma unroll
      for (int j = 0; j < 4; ++j) {
        const int gj = bc + c0 + j;
        grA[j] = load_cell(sub, giA, gj, s0, rbuf, start, i0, i1, j0, j1, ri0, rj0);
        if (rowBok)
          grB[j] = load_cell(sub, giB, gj, s0, rbuf, start, i0, i1, j0, j1, ri0, rj0);
      }
      *reinterpret_cast<f32x4*>(&Lg[0][(wA + 1) * LSTR + c0 + 4]) = grA;
      if (rowBok) *reinterpret_cast<f32x4*>(&Lg[0][(wB + 1) * LSTR + c0 + 4]) = grB;
    }
    __syncthreads();

    if (bact) {
      // cost vectors for both rows: 16 named f32x4 (spill-safe pattern from R6)
      f32x4 cA0, cA1, cA2, cA3, cA4, cA5, cA6, cA7;
      f32x4 cB0, cB1, cB2, cB3, cB4, cB5, cB6, cB7;
      if (act) {
        const int cbA = wA * CPL + c0;
        cA0 = *reinterpret_cast<const f32x4*>(&Lc[0][cbA]);
        cA1 = *reinterpret_cast<const f32x4*>(&Lc[1][cbA]);
        cA2 = *reinterpret_cast<const f32x4*>(&Lc[2][cbA]);
        cA3 = *reinterpret_cast<const f32x4*>(&Lc[3][cbA]);
        cA4 = *reinterpret_cast<const f32x4*>(&Lc[4][cbA]);
        cA5 = *reinterpret_cast<const f32x4*>(&Lc[5][cbA]);
        cA6 = *reinterpret_cast<const f32x4*>(&Lc[6][cbA]);
        cA7 = *reinterpret_cast<const f32x4*>(&Lc[7][cbA]);
        if (rowBok) {
          const int cbB = wB * CPL + c0;
          cB0 = *reinterpret_cast<const f32x4*>(&Lc[0][cbB]);
          cB1 = *reinterpret_cast<const f32x4*>(&Lc[1][cbB]);
          cB2 = *reinterpret_cast<const f32x4*>(&Lc[2][cbB]);
          cB3 = *reinterpret_cast<const f32x4*>(&Lc[3][cbB]);
          cB4 = *reinterpret_cast<const f32x4*>(&Lc[4][cbB]);
          cB5 = *reinterpret_cast<const f32x4*>(&Lc[5][cbB]);
          cB6 = *reinterpret_cast<const f32x4*>(&Lc[6][cbB]);
          cB7 = *reinterpret_cast<const f32x4*>(&Lc[7][cbB]);
        } else {
          f32x4 bg; bg[0] = BIGC; bg[1] = BIGC; bg[2] = BIGC; bg[3] = BIGC;
          cB0 = bg; cB1 = bg; cB2 = bg; cB3 = bg; cB4 = bg; cB5 = bg; cB6 = bg; cB7 = bg;
        }
      }

      for (int t = 0; t < nk; ++t) {
        float* __restrict__ Lp = Lg[t & 1];
        float* __restrict__ Lq = Lg[(t + 1) & 1];

        if (tAny) {   // replicate-pad refresh (border tiles only; cold in harness)
          if (tN) for (int k = tid; k < (n0 + 1) * LSTR; k += BD) {
            const int r = k / LSTR, c = k - r * LSTR;
            Lp[r * LSTR + c] = Lp[(n0 + 1) * LSTR + c];
          }
          if (tS) {
            const int base = sLast + 2, cnt = (LROWS - 1) - base;
            for (int k = tid; k < cnt * LSTR; k += BD) {
              const int r = base + k / LSTR, c = k - (k / LSTR) * LSTR;
              Lp[r * LSTR + c] = Lp[(sLast + 1) * LSTR + c];
            }
          }
          __syncthreads();
          if (tW) {
            const int cn = w0 + 1;
            for (int k = tid; k < (LROWS - 1) * cn; k += BD) {
              const int r = k / cn, c = 3 + (k - (k / cn) * cn);
              Lp[r * LSTR + c] = Lp[r * LSTR + w0 + 4];
            }
          }
          if (tE) {
            const int cbase = eLast + 5, cn = 58 - cbase;
            for (int k = tid; k < (LROWS - 1) * cn; k += BD) {
              const int r = k / cn, c = cbase + (k - (k / cn) * cn);
              Lp[r * LSTR + c] = Lp[r * LSTR + eLast + 4];
            }
          }
          __syncthreads();
        }

        const int sg = s0 + t;
        if (act && (sg + 1 >= ds)) {
          // Lg rows: wA = halo above; wA+1,wA+2 = own (regs); wA+3 = halo below
          const int bT = wA * LSTR + c0, bO = (wA + 1) * LSTR + c0;
          const int bU = (wA + 2) * LSTR + c0, bD = (wA + 3) * LSTR + c0;
          const f32x4 top = *reinterpret_cast<const f32x4*>(&Lp[bT + 4]);
          const f32x4 bot = *reinterpret_cast<const f32x4*>(&Lp[bD + 4]);
          const float eT0 = Lp[bT + 3], eT1 = Lp[bT + 8];   // adjacent pair -> ds_read2
          const float eA0 = Lp[bO + 3], eA1 = Lp[bO + 8];
          const float eB0 = Lp[bU + 3], eB1 = Lp[bU + 8];
          const float eD0 = Lp[bD + 3], eD1 = Lp[bD + 8];
          float VT[6] = { eT0, top[0], top[1], top[2], top[3], eT1 };
          float VA[6] = { eA0, grA[0], grA[1], grA[2], grA[3], eA1 };
          float VB[6] = { eB0, grB[0], grB[1], grB[2], grB[3], eB1 };
          float VD[6] = { eD0, bot[0], bot[1], bot[2], bot[3], eD1 };

#define UPD1(gr, UP, OWN, DN, C0v, C1v, C2v, C3v, C4v, C5v, C6v, C7v, j)       \
  do {                                                                          \
    const float a0 = UP[j]     + C0v[j]; const float a1 = OWN[j]    + C1v[j];  \
    const float a2 = DN[j]     + C2v[j]; const float a3 = UP[j + 1] + C3v[j];  \
    const float a4 = DN[j + 1] + C4v[j]; const float a5 = UP[j + 2] + C5v[j];  \
    const float a6 = OWN[j + 2]+ C6v[j]; const float a7 = DN[j + 2] + C7v[j];  \
    const float m01 = fminf(a0, a1), m23 = fminf(a2, a3);                      \
    const float m45 = fminf(a4, a5), m67 = fminf(a6, a7);                      \
    gr[j] = fminf(gr[j], fminf(fminf(m01, m23), fminf(m45, m67)));             \
  } while (0)

          UPD1(grA, VT, VA, VB, cA0, cA1, cA2, cA3, cA4, cA5, cA6, cA7, 0);
          UPD1(grA, VT, VA, VB, cA0, cA1, cA2, cA3, cA4, cA5, cA6, cA7, 1);
          UPD1(grA, VT, VA, VB, cA0, cA1, cA2, cA3, cA4, cA5, cA6, cA7, 2);
          UPD1(grA, VT, VA, VB, cA0, cA1, cA2, cA3, cA4, cA5, cA6, cA7, 3);
          UPD1(grB, VA, VB, VD, cB0, cB1, cB2, cB3, cB4, cB5, cB6, cB7, 0);
          UPD1(grB, VA, VB, VD, cB0, cB1, cB2, cB3, cB4, cB5, cB6, cB7, 1);
          UPD1(grB, VA, VB, VD, cB0, cB1, cB2, cB3, cB4, cB5, cB6, cB7, 2);
          UPD1(grB, VA, VB, VD, cB0, cB1, cB2, cB3, cB4, cB5, cB6, cB7, 3);
#undef UPD1
          *reinterpret_cast<f32x4*>(&Lq[bO + 4]) = grA;
          if (rowBok) *reinterpret_cast<f32x4*>(&Lq[bU + 4]) = grB;
        }
        __syncthreads();
      }

      // writeback owned cells to wbuf (mid chunks) or g (last chunk)
      if (act) {
#pragma unroll
        for (int rsel = 0; rsel < 2; ++rsel) {
          const int wi = rsel ? wB : wA;
          if ((rsel == 0 || rowBok) && wi >= KS && wi < KS + TS) {
            const int gi = br + wi;
            if (gi <= ri1) {
#pragma unroll
              for (int j = 0; j < 4; ++j) {
                const int wj = c0 + j;
                if (wj >= KS && wj < KS + TS) {
                  const int gj = bc + wj;
                  if (gj <= rj1) {
                    const float v = rsel ? grB[j] : grA[j];
                    if (lastC) g[gi * WW + gj] = v;
                    else       wbuf[(gi - ri0) * RSTR + (gj - rj0)] = v;
                  }
                }
              }
            }
          }
        }
      }
    }
    if (!lastC) grid.sync();   // chunk writes visible before next chunk's reload
  }
}

extern "C" void kernel_launch(void* const* d_in, const int* in_sizes, int n_in,
                              void* d_out, int out_size, void* d_ws, size_t ws_size,
                              hipStream_t stream)
{
  const float* ob = (const float*)d_in[0];   // obstacles
  const float* co = (const float*)d_in[1];   // coords (y plane, x plane)
  const float* st = (const float*)d_in[2];   // start_map
  // d_in[3] = goal_map: dead w.r.t. returned g
  const int* nsp  = (const int*)d_in[4];     // num_steps
  float* g = (float*)d_out;

  unsigned* bbslice = (unsigned*)d_ws;                         // 64*16 B = 1 KB
  const size_t BUFB = (size_t)RSTR * RSTR * sizeof(float);     // 73984 B
  float* bufA = (float*)((char*)d_ws + 1024);
  float* bufB = (float*)((char*)d_ws + 1024 + BUFB);
  float* wsg  = (float*)((char*)d_ws + 1024 + 2 * BUFB);       // fallback only
  const int ws_ok = (ws_size >= 1024 + 2 * BUFB + (size_t)HH * WW * sizeof(float)) ? 1 : 0;

  void* args[10];
  args[0] = (void*)&ob;  args[1] = (void*)&co;   args[2] = (void*)&st;
  args[3] = (void*)&g;   args[4] = (void*)&nsp;  args[5] = (void*)&bbslice;
  args[6] = (void*)&bufA; args[7] = (void*)&bufB; args[8] = (void*)&wsg;
  args[9] = (void*)&ws_ok;
  hipLaunchCooperativeKernel((void*)k_all, dim3(NBLK), dim3(BD), args, 0, stream);
}